// Round 8
// baseline (182.790 us; speedup 1.0000x reference)
//
#include <hip/hip_runtime.h>
#include <stdint.h>

#define DI __device__ __forceinline__

typedef __attribute__((ext_vector_type(8))) short short8;
typedef __attribute__((ext_vector_type(8))) __bf16 bf16x8;
typedef __attribute__((ext_vector_type(2))) __bf16 bf16x2;
typedef __attribute__((ext_vector_type(4))) float f32x4;
typedef unsigned short u16;

static constexpr int SEQ = 2048;
static constexpr int EMB = 1024;

// round-to-nearest-even fp32 -> bf16
DI u16 f2bf(float x) {
  uint32_t u = __float_as_uint(x);
  u += 0x7fffu + ((u >> 16) & 1u);
  return (u16)(u >> 16);
}

DI uint32_t pkbf(float a, float b) {
#if __has_builtin(__builtin_amdgcn_cvt_pk_bf16_f32)
  bf16x2 v = __builtin_amdgcn_cvt_pk_bf16_f32(a, b);
  return __builtin_bit_cast(uint32_t, v);
#else
  return (uint32_t)f2bf(a) | ((uint32_t)f2bf(b) << 16);
#endif
}

DI float fexp2(float x) {
#if __has_builtin(__builtin_amdgcn_exp2f)
  return __builtin_amdgcn_exp2f(x);
#else
  return exp2f(x);
#endif
}

DI f32x4 mfma16(short8 a, short8 b, f32x4 c) {
  return __builtin_amdgcn_mfma_f32_16x16x32_bf16(
      __builtin_bit_cast(bf16x8, a), __builtin_bit_cast(bf16x8, b), c, 0, 0, 0);
}

// async global->LDS, 16B per lane; LDS dest = wave-uniform base + lane*16
DI void g2l16(const u16* g, u16* l) {
  __builtin_amdgcn_global_load_lds(
      (const __attribute__((address_space(1))) unsigned int*)g,
      (__attribute__((address_space(3))) unsigned int*)l, 16, 0, 0);
}

// explicit drain of outstanding vector-memory ops (incl. LDS-DMA writes):
// simm16 = lgkm(15)<<8 | exp(7)<<4 | vm(0) -> waits vmcnt only.
DI void wait_vm0() { __builtin_amdgcn_s_waitcnt(0x0F70); }

// ---------------- fused fp32 -> bf16 conversion (all 5 tensors) ----------------
__global__ __launch_bounds__(256) void cvt_all(
    const float* __restrict__ x,  const float* __restrict__ wq,
    const float* __restrict__ wk, const float* __restrict__ wv,
    const float* __restrict__ wo,
    u16* __restrict__ xb, u16* __restrict__ wqb, u16* __restrict__ wkb,
    u16* __restrict__ wvb, u16* __restrict__ wob) {
  const int bx = blockIdx.x;
  const float* s; u16* d; int off;
  if (bx < 4096) { s = x; d = xb; off = bx << 8; }
  else {
    const int r = bx - 4096, wsel = r >> 10;
    off = (r & 1023) << 8;
    s = wsel == 0 ? wq : (wsel == 1 ? wk : (wsel == 2 ? wv : wo));
    d = wsel == 0 ? wqb : (wsel == 1 ? wkb : (wsel == 2 ? wvb : wob));
  }
  const int i = off + threadIdx.x;
  float4 v = ((const float4*)s)[i];
  uint2 o;
  o.x = pkbf(v.x, v.y);
  o.y = pkbf(v.z, v.w);
  ((uint2*)d)[i] = o;
}

// ------- double-buffered GEMM K-loop, BK=32: C[128 x NB*32] = A * B^T, K=1024
// Prefetch tile ks+1 into the other LDS half, THEN compute tile ks, THEN
// drain + ONE barrier. XOR chunk swizzle: LDS chunk c of a row holds global
// chunk c ^ ((row>>1)&3); frag read offset (g ^ ((L>>1)&3)) is lane-only.
template <int NB>   // b-subtiles per wave: 4 -> BN=128, 2 -> BN=64
DI void gemm_core_db(const u16* __restrict__ A, const u16* __restrict__ B,
                     int m0, int n0, u16* Al, u16* Bl, f32x4 (&acc)[4][NB],
                     int t) {
  const int L = t & 63, w = t >> 6;
  const int wm = (w >> 1) * 64, wn = (w & 1) * (NB * 16);
  const int r = L & 15, g = L >> 4;
  const int gofs = (g ^ ((L >> 1) & 3)) * 8;
  const int scol = (((t & 3) ^ ((t >> 3) & 3)) * 8);
  const int arow0 = t >> 2, arow1 = (t + 256) >> 2;
  const u16* Ap0 = A + ((size_t)(m0 + arow0) << 10) + scol;
  const u16* Ap1 = A + ((size_t)(m0 + arow1) << 10) + scol;
  const u16* Bp0 = B + ((size_t)(n0 + arow0) << 10) + scol;
  const u16* Bp1 = B + ((size_t)(n0 + arow1) << 10) + scol;
  constexpr int AH = 128 * 32;      // elems per A half
  constexpr int BH = NB * 32 * 32;  // elems per B half

  // prologue: stage tile 0 into half 0
  g2l16(Ap0, Al + t * 8);
  g2l16(Ap1, Al + (t + 256) * 8);
  g2l16(Bp0, Bl + t * 8);
  if (NB == 4) g2l16(Bp1, Bl + (t + 256) * 8);
  wait_vm0();
  __syncthreads();

  for (int ks = 0; ks < 32; ++ks) {
    const int cur = ks & 1;
    const u16* Alc = Al + cur * AH;
    const u16* Blc = Bl + cur * BH;
    if (ks < 31) {                        // prefetch tile ks+1 (async, no wait)
      const int k0 = (ks + 1) * 32;
      u16* Aln = Al + (cur ^ 1) * AH;
      u16* Bln = Bl + (cur ^ 1) * BH;
      g2l16(Ap0 + k0, Aln + t * 8);
      g2l16(Ap1 + k0, Aln + (t + 256) * 8);
      g2l16(Bp0 + k0, Bln + t * 8);
      if (NB == 4) g2l16(Bp1 + k0, Bln + (t + 256) * 8);
    }
    short8 af[4], bfr[NB];
#pragma unroll
    for (int mt = 0; mt < 4; ++mt)
      af[mt] = *(const short8*)(Alc + (wm + mt * 16 + r) * 32 + gofs);
#pragma unroll
    for (int nt = 0; nt < NB; ++nt)
      bfr[nt] = *(const short8*)(Blc + (wn + nt * 16 + r) * 32 + gofs);
#pragma unroll
    for (int mt = 0; mt < 4; ++mt)
#pragma unroll
      for (int nt = 0; nt < NB; ++nt)
        acc[mt][nt] = mfma16(af[mt], bfr[nt], acc[mt][nt]);
    if (ks < 31) {
      wait_vm0();                         // prefetch landed (after compute!)
      __syncthreads();                    // one barrier per iter
    }
  }
}

// ---------------- fused QKV projection ----------------
__global__ __launch_bounds__(256) void gemm_qkv(
    const u16* __restrict__ xb,
    const u16* __restrict__ wqb, const u16* __restrict__ wkb,
    const u16* __restrict__ wvb,
    u16* __restrict__ Qb, u16* __restrict__ Kb, u16* __restrict__ Vt) {
  __shared__ u16 Al[2 * 128 * 32];
  __shared__ u16 Bl[2 * 128 * 32];
  const int t = threadIdx.x, L = t & 63, w = t >> 6;
  const int wm = (w >> 1) * 64, wn = (w & 1) * 64;
  const int bx = blockIdx.x;
  const int m0 = (bx & 31) * 128;
  const int n0 = (bx >> 5) * 128;
  const int which = n0 >> 10;                 // 0:Q 1:K 2:V
  const u16* wsel = which == 0 ? wqb : (which == 1 ? wkb : wvb);
  const int nl0 = n0 & 1023;

  f32x4 acc[4][4];
#pragma unroll
  for (int i = 0; i < 4; ++i)
#pragma unroll
    for (int j = 0; j < 4; ++j) acc[i][j] = f32x4{0.f, 0.f, 0.f, 0.f};

  gemm_core_db<4>(xb, wsel, m0, nl0, Al, Bl, acc, t);

  const int rl = (L >> 4) * 4, cl = L & 15;
  if (which < 2) {
    u16* outp = which == 0 ? Qb : Kb;
    // fold 1/sqrt(64) * log2(e) into Q (softmax runs in exp2 domain)
    const float sc = which == 0 ? 0.125f * 1.44269504089f : 1.0f;
#pragma unroll
    for (int mt = 0; mt < 4; ++mt) {
#pragma unroll
      for (int nt = 0; nt < 4; ++nt) {
        const int n = nl0 + wn + nt * 16 + cl;
#pragma unroll
        for (int r = 0; r < 4; ++r) {
          const int m = m0 + wm + mt * 16 + rl + r;
          outp[(size_t)m * EMB + n] = f2bf(acc[mt][nt][r] * sc);
        }
      }
    }
  } else {
    // V: write transposed per head: Vt[(b*16+h)*64 + d][s]
#pragma unroll
    for (int mt = 0; mt < 4; ++mt) {
      const int mbase = m0 + wm + mt * 16 + rl;
      const int b = mbase >> 11, s = mbase & 2047;
#pragma unroll
      for (int nt = 0; nt < 4; ++nt) {
        const int n = nl0 + wn + nt * 16 + cl;
        const int h = n >> 6, d = n & 63;
        uint2 o;
        o.x = pkbf(acc[mt][nt][0], acc[mt][nt][1]);
        o.y = pkbf(acc[mt][nt][2], acc[mt][nt][3]);
        *(uint2*)(Vt + ((size_t)((b * 16 + h) * 64 + d) << 11) + s) = o;
      }
    }
  }
}

// ---------- flash attention (causal), 256 threads / 4 waves, K/V dbuf --------
// q-tile 64 (wave w owns q rows w*16..+15), grid 1024 = (32 bh) x (32 qt),
// LPT order (big qt first). Double-buffered K/V tiles: prefetch kt+1, compute
// kt, drain AFTER compute, one barrier per tile (gemm_core_db pattern).
// No-max softmax in exp2 domain; P round-trips per-wave-private Pl rows.
// LDS 73 KB -> 2 blocks/CU.
__global__ __launch_bounds__(256, 2) void attn(
    const u16* __restrict__ Qb, const u16* __restrict__ Kb,
    const u16* __restrict__ Vt, u16* __restrict__ Ob) {
  __shared__ u16 Kl[2 * 128 * 64];   // [buf][key][64], XOR-8 swizzled
  __shared__ u16 Vl[2 * 64 * 128];   // [buf][d][128], XOR-8 swizzled
  __shared__ u16 Pl[64 * 72];        // [q][64+pad]; also Q staging (linear)

  const int t = threadIdx.x, w = t >> 6, L = t & 63;
  const int g = L >> 4, cl = L & 15;
  const int qrow = w * 16 + cl;
  const int gk = g ^ (cl & 3);          // swizzled low chunk bits for frag reads
  const int khi = (cl >> 2) & 1;        // swizzled high chunk bit

  // LPT mapping: first 512 blocks get qt 31..16 (big), rest 0..15 (small)
  const int idx = blockIdx.x;
  int bh, qt;
  if (idx < 512) { bh = idx & 31; qt = 31 - (idx >> 5); }
  else           { int r = idx - 512; bh = r & 31; qt = r >> 5; }
  const int b = bh >> 4, h = bh & 15;
  const int q0 = qt * 64;
  const int qglob = q0 + qrow;
  const int nkt = (qt >> 1) + 1;        // 128-key tiles needed
  const bool evenq = (qt & 1) == 0;

  const u16* Qg = Qb + ((size_t)(b * SEQ) << 10) + h * 64;
  const u16* Kg = Kb + ((size_t)(b * SEQ) << 10) + h * 64;
  const u16* Vg = Vt + ((size_t)(bh * 64) << 11);

  // prologue: stage Q (512 chunks) into Pl linear + K0/V0 into buf 0
#pragma unroll
  for (int i = 0; i < 2; ++i) {
    const int c = t + i * 256;
    const int row = c >> 3, col = ((c & 7) ^ (row & 7)) * 8;
    g2l16(Qg + ((size_t)(q0 + row) << 10) + col, Pl + c * 8);
  }
#pragma unroll
  for (int i = 0; i < 4; ++i) {
    const int c = t + i * 256;
    const int row = c >> 3, col = ((c & 7) ^ (row & 7)) * 8;
    g2l16(Kg + ((size_t)row << 10) + col, Kl + c * 8);
  }
#pragma unroll
  for (int i = 0; i < 4; ++i) {
    const int c = t + i * 256;
    const int vrow = c >> 4, vsc = ((c & 15) ^ (vrow & 7)) * 8;
    g2l16(Vg + ((size_t)vrow << 11) + vsc, Vl + c * 8);
  }
  wait_vm0();
  __syncthreads();

  short8 qf[2];
#pragma unroll
  for (int ks = 0; ks < 2; ++ks)
    qf[ks] = *(const short8*)(Pl + qrow * 64 + ((ks ^ khi) * 4 + gk) * 8);

  float lp = 0.f;
  f32x4 oacc[4];
#pragma unroll
  for (int dt = 0; dt < 4; ++dt) oacc[dt] = f32x4{0.f, 0.f, 0.f, 0.f};

  for (int kt = 0; kt < nkt; ++kt) {
    const int cur = kt & 1;
    const u16* Klc = Kl + cur * (128 * 64);
    const u16* Vlc = Vl + cur * (64 * 128);
    if (kt + 1 < nkt) {                 // prefetch next K/V tile (async)
      const int k0n = (kt + 1) * 128;
      u16* Kln = Kl + (cur ^ 1) * (128 * 64);
      u16* Vln = Vl + (cur ^ 1) * (64 * 128);
#pragma unroll
      for (int i = 0; i < 4; ++i) {
        const int c = t + i * 256;
        const int row = c >> 3, col = ((c & 7) ^ (row & 7)) * 8;
        g2l16(Kg + ((size_t)(k0n + row) << 10) + col, Kln + c * 8);
      }
#pragma unroll
      for (int i = 0; i < 4; ++i) {
        const int c = t + i * 256;
        const int vrow = c >> 4, vsc = ((c & 15) ^ (vrow & 7)) * 8;
        g2l16(Vg + ((size_t)vrow << 11) + k0n + vsc, Vln + c * 8);
      }
    }
    const bool last = (kt == nkt - 1);
    const int k0 = kt * 128;

#pragma unroll
    for (int hh = 0; hh < 2; ++hh) {
      const bool skip = last && evenq && (hh == 1);  // fully-masked half
      if (!skip) {
        const bool maskit = last && (evenq ? (hh == 0) : (hh == 1));
        // S^T half: 64 keys x 16 q
        f32x4 sacc[4];
#pragma unroll
        for (int mt = 0; mt < 4; ++mt) sacc[mt] = f32x4{0.f, 0.f, 0.f, 0.f};
#pragma unroll
        for (int ks = 0; ks < 2; ++ks)
#pragma unroll
          for (int mt = 0; mt < 4; ++mt) {
            short8 kf = *(const short8*)(
                Klc + ((hh * 4 + mt) * 16 + cl) * 64 + ((ks ^ khi) * 4 + gk) * 8);
            sacc[mt] = mfma16(kf, qf[ks], sacc[mt]);
          }
        // softmax (exp2 domain, no running max), P into private Pl rows
#pragma unroll
        for (int mt = 0; mt < 4; ++mt) {
          const int keyg = k0 + hh * 64 + mt * 16 + g * 4;
          float p0 = fexp2(sacc[mt][0]);
          float p1 = fexp2(sacc[mt][1]);
          float p2 = fexp2(sacc[mt][2]);
          float p3 = fexp2(sacc[mt][3]);
          if (maskit) {
            if (keyg + 0 > qglob) p0 = 0.f;
            if (keyg + 1 > qglob) p1 = 0.f;
            if (keyg + 2 > qglob) p2 = 0.f;
            if (keyg + 3 > qglob) p3 = 0.f;
          }
          lp += (p0 + p1) + (p2 + p3);
          uint2 pk;
          pk.x = pkbf(p0, p1);
          pk.y = pkbf(p2, p3);
          *(uint2*)(Pl + qrow * 72 + mt * 16 + g * 4) = pk;
        }
        // O^T half += V^T * P^T
#pragma unroll
        for (int ks = 0; ks < 2; ++ks) {
          short8 pf = *(const short8*)(Pl + qrow * 72 + ks * 32 + g * 8);
#pragma unroll
          for (int dt = 0; dt < 4; ++dt) {
            short8 vf = *(const short8*)(
                Vlc + (dt * 16 + cl) * 128 + (hh * 8 + (ks ^ khi) * 4 + gk) * 8);
            oacc[dt] = mfma16(vf, pf, oacc[dt]);
          }
        }
      }
    }
    if (kt + 1 < nkt) {
      wait_vm0();                       // prefetch landed (after compute)
      __syncthreads();                  // one barrier per tile
    }
  }

  // reduce l over the 4 key-quarter lanes, then write O
  float l = lp;
  l += __shfl_xor(l, 16);
  l += __shfl_xor(l, 32);
  const float inv = 1.f / l;
  const size_t qg = (size_t)(b * SEQ + qglob);
#pragma unroll
  for (int dt = 0; dt < 4; ++dt) {
    uint2 o;
    o.x = pkbf(oacc[dt][0] * inv, oacc[dt][1] * inv);
    o.y = pkbf(oacc[dt][2] * inv, oacc[dt][3] * inv);
    *(uint2*)(Ob + (qg << 10) + h * 64 + dt * 16 + g * 4) = o;
  }
}

// ---------------- output projection: fp32 out = Ob * wo^T, 128x64 tiles ------
__global__ __launch_bounds__(256) void gemm_out(const u16* __restrict__ Ab,
                                                const u16* __restrict__ Wb,
                                                float* __restrict__ out) {
  __shared__ u16 Al[2 * 128 * 32];
  __shared__ u16 Bl[2 * 64 * 32];
  const int t = threadIdx.x, L = t & 63, w = t >> 6;
  const int wm = (w >> 1) * 64, wn = (w & 1) * 32;
  const int bx = blockIdx.x;
  const int m0 = (bx & 31) * 128;
  const int n0 = (bx >> 5) * 64;

  f32x4 acc[4][2];
#pragma unroll
  for (int i = 0; i < 4; ++i)
#pragma unroll
    for (int j = 0; j < 2; ++j) acc[i][j] = f32x4{0.f, 0.f, 0.f, 0.f};

  gemm_core_db<2>(Ab, Wb, m0, n0, Al, Bl, acc, t);

  const int rl = (L >> 4) * 4, cl = L & 15;
#pragma unroll
  for (int mt = 0; mt < 4; ++mt)
#pragma unroll
    for (int nt = 0; nt < 2; ++nt) {
      const int n = n0 + wn + nt * 16 + cl;
#pragma unroll
      for (int r = 0; r < 4; ++r) {
        const int m = m0 + wm + mt * 16 + rl + r;
        out[(size_t)m * EMB + n] = acc[mt][nt][r];
      }
    }
}

// ---------------- launch ----------------
extern "C" void kernel_launch(void* const* d_in, const int* in_sizes, int n_in,
                              void* d_out, int out_size, void* d_ws, size_t ws_size,
                              hipStream_t stream) {
  const float* x  = (const float*)d_in[0];
  const float* wq = (const float*)d_in[1];
  const float* wk = (const float*)d_in[2];
  const float* wv = (const float*)d_in[3];
  const float* wo = (const float*)d_in[4];
  float* out = (float*)d_out;

  char* ws = (char*)d_ws;
  u16* xb  = (u16*)(ws);                          // 8 MB  [4096][1024]
  u16* wqb = (u16*)(ws + ((size_t)8  << 20));     // 2 MB
  u16* wkb = (u16*)(ws + ((size_t)10 << 20));     // 2 MB
  u16* wvb = (u16*)(ws + ((size_t)12 << 20));     // 2 MB
  u16* wob = (u16*)(ws + ((size_t)14 << 20));     // 2 MB
  u16* Qb  = (u16*)(ws + ((size_t)16 << 20));     // 8 MB  pre-scaled by 0.125*log2e
  u16* Kb  = (u16*)(ws + ((size_t)24 << 20));     // 8 MB
  u16* Vt  = (u16*)(ws + ((size_t)32 << 20));     // 8 MB  [32*64][2048] transposed
  u16* Ob  = (u16*)(ws + ((size_t)40 << 20));     // 8 MB

  cvt_all<<<8192, 256, 0, stream>>>(x, wq, wk, wv, wo, xb, wqb, wkb, wvb, wob);
  gemm_qkv<<<768, 256, 0, stream>>>(xb, wqb, wkb, wvb, Qb, Kb, Vt);
  attn<<<1024, 256, 0, stream>>>(Qb, Kb, Vt, Ob);
  gemm_out<<<512, 256, 0, stream>>>(Ob, wob, out);
}

// Round 9
// 175.196 us; speedup vs baseline: 1.0433x; 1.0433x over previous
//
#include <hip/hip_runtime.h>
#include <stdint.h>

#define DI __device__ __forceinline__

typedef __attribute__((ext_vector_type(8))) short short8;
typedef __attribute__((ext_vector_type(8))) __bf16 bf16x8;
typedef __attribute__((ext_vector_type(2))) __bf16 bf16x2;
typedef __attribute__((ext_vector_type(4))) float f32x4;
typedef unsigned short u16;

static constexpr int SEQ = 2048;
static constexpr int EMB = 1024;

// round-to-nearest-even fp32 -> bf16
DI u16 f2bf(float x) {
  uint32_t u = __float_as_uint(x);
  u += 0x7fffu + ((u >> 16) & 1u);
  return (u16)(u >> 16);
}

DI uint32_t pkbf(float a, float b) {
#if __has_builtin(__builtin_amdgcn_cvt_pk_bf16_f32)
  bf16x2 v = __builtin_amdgcn_cvt_pk_bf16_f32(a, b);
  return __builtin_bit_cast(uint32_t, v);
#else
  return (uint32_t)f2bf(a) | ((uint32_t)f2bf(b) << 16);
#endif
}

DI float fexp2(float x) {
#if __has_builtin(__builtin_amdgcn_exp2f)
  return __builtin_amdgcn_exp2f(x);
#else
  return exp2f(x);
#endif
}

DI f32x4 mfma16(short8 a, short8 b, f32x4 c) {
  return __builtin_amdgcn_mfma_f32_16x16x32_bf16(
      __builtin_bit_cast(bf16x8, a), __builtin_bit_cast(bf16x8, b), c, 0, 0, 0);
}

// async global->LDS, 16B per lane; LDS dest = wave-uniform base + lane*16
DI void g2l16(const u16* g, u16* l) {
  __builtin_amdgcn_global_load_lds(
      (const __attribute__((address_space(1))) unsigned int*)g,
      (__attribute__((address_space(3))) unsigned int*)l, 16, 0, 0);
}

// explicit drain of outstanding vector-memory ops (incl. LDS-DMA writes):
// simm16 = lgkm(15)<<8 | exp(7)<<4 | vm(0) -> waits vmcnt only.
DI void wait_vm0() { __builtin_amdgcn_s_waitcnt(0x0F70); }

// ---------------- fused fp32 -> bf16 conversion (all 5 tensors) ----------------
__global__ __launch_bounds__(256) void cvt_all(
    const float* __restrict__ x,  const float* __restrict__ wq,
    const float* __restrict__ wk, const float* __restrict__ wv,
    const float* __restrict__ wo,
    u16* __restrict__ xb, u16* __restrict__ wqb, u16* __restrict__ wkb,
    u16* __restrict__ wvb, u16* __restrict__ wob) {
  const int bx = blockIdx.x;
  const float* s; u16* d; int off;
  if (bx < 4096) { s = x; d = xb; off = bx << 8; }
  else {
    const int r = bx - 4096, wsel = r >> 10;
    off = (r & 1023) << 8;
    s = wsel == 0 ? wq : (wsel == 1 ? wk : (wsel == 2 ? wv : wo));
    d = wsel == 0 ? wqb : (wsel == 1 ? wkb : (wsel == 2 ? wvb : wob));
  }
  const int i = off + threadIdx.x;
  float4 v = ((const float4*)s)[i];
  uint2 o;
  o.x = pkbf(v.x, v.y);
  o.y = pkbf(v.z, v.w);
  ((uint2*)d)[i] = o;
}

// ------- double-buffered GEMM K-loop, BK=32: C[128 x NB*32] = A * B^T, K=1024
// Prefetch tile ks+1 into the other LDS half, THEN compute tile ks, THEN
// drain + ONE barrier. XOR chunk swizzle: LDS chunk c of a row holds global
// chunk c ^ ((row>>1)&3); frag read offset (g ^ ((L>>1)&3)) is lane-only.
template <int NB>   // b-subtiles per wave: 4 -> BN=128, 2 -> BN=64
DI void gemm_core_db(const u16* __restrict__ A, const u16* __restrict__ B,
                     int m0, int n0, u16* Al, u16* Bl, f32x4 (&acc)[4][NB],
                     int t) {
  const int L = t & 63, w = t >> 6;
  const int wm = (w >> 1) * 64, wn = (w & 1) * (NB * 16);
  const int r = L & 15, g = L >> 4;
  const int gofs = (g ^ ((L >> 1) & 3)) * 8;
  const int scol = (((t & 3) ^ ((t >> 3) & 3)) * 8);
  const int arow0 = t >> 2, arow1 = (t + 256) >> 2;
  const u16* Ap0 = A + ((size_t)(m0 + arow0) << 10) + scol;
  const u16* Ap1 = A + ((size_t)(m0 + arow1) << 10) + scol;
  const u16* Bp0 = B + ((size_t)(n0 + arow0) << 10) + scol;
  const u16* Bp1 = B + ((size_t)(n0 + arow1) << 10) + scol;
  constexpr int AH = 128 * 32;      // elems per A half
  constexpr int BH = NB * 32 * 32;  // elems per B half

  // prologue: stage tile 0 into half 0
  g2l16(Ap0, Al + t * 8);
  g2l16(Ap1, Al + (t + 256) * 8);
  g2l16(Bp0, Bl + t * 8);
  if (NB == 4) g2l16(Bp1, Bl + (t + 256) * 8);
  wait_vm0();
  __syncthreads();

  for (int ks = 0; ks < 32; ++ks) {
    const int cur = ks & 1;
    const u16* Alc = Al + cur * AH;
    const u16* Blc = Bl + cur * BH;
    if (ks < 31) {                        // prefetch tile ks+1 (async, no wait)
      const int k0 = (ks + 1) * 32;
      u16* Aln = Al + (cur ^ 1) * AH;
      u16* Bln = Bl + (cur ^ 1) * BH;
      g2l16(Ap0 + k0, Aln + t * 8);
      g2l16(Ap1 + k0, Aln + (t + 256) * 8);
      g2l16(Bp0 + k0, Bln + t * 8);
      if (NB == 4) g2l16(Bp1 + k0, Bln + (t + 256) * 8);
    }
    short8 af[4], bfr[NB];
#pragma unroll
    for (int mt = 0; mt < 4; ++mt)
      af[mt] = *(const short8*)(Alc + (wm + mt * 16 + r) * 32 + gofs);
#pragma unroll
    for (int nt = 0; nt < NB; ++nt)
      bfr[nt] = *(const short8*)(Blc + (wn + nt * 16 + r) * 32 + gofs);
#pragma unroll
    for (int mt = 0; mt < 4; ++mt)
#pragma unroll
      for (int nt = 0; nt < NB; ++nt)
        acc[mt][nt] = mfma16(af[mt], bfr[nt], acc[mt][nt]);
    if (ks < 31) {
      wait_vm0();                         // prefetch landed (after compute!)
      __syncthreads();                    // one barrier per iter
    }
  }
}

// ---------------- fused QKV projection ----------------
__global__ __launch_bounds__(256) void gemm_qkv(
    const u16* __restrict__ xb,
    const u16* __restrict__ wqb, const u16* __restrict__ wkb,
    const u16* __restrict__ wvb,
    u16* __restrict__ Qb, u16* __restrict__ Kb, u16* __restrict__ Vt) {
  __shared__ u16 Al[2 * 128 * 32];
  __shared__ u16 Bl[2 * 128 * 32];
  const int t = threadIdx.x, L = t & 63, w = t >> 6;
  const int wm = (w >> 1) * 64, wn = (w & 1) * 64;
  const int bx = blockIdx.x;
  const int m0 = (bx & 31) * 128;
  const int n0 = (bx >> 5) * 128;
  const int which = n0 >> 10;                 // 0:Q 1:K 2:V
  const u16* wsel = which == 0 ? wqb : (which == 1 ? wkb : wvb);
  const int nl0 = n0 & 1023;

  f32x4 acc[4][4];
#pragma unroll
  for (int i = 0; i < 4; ++i)
#pragma unroll
    for (int j = 0; j < 4; ++j) acc[i][j] = f32x4{0.f, 0.f, 0.f, 0.f};

  gemm_core_db<4>(xb, wsel, m0, nl0, Al, Bl, acc, t);

  const int rl = (L >> 4) * 4, cl = L & 15;
  if (which < 2) {
    u16* outp = which == 0 ? Qb : Kb;
    // fold 1/sqrt(64) * log2(e) into Q (softmax runs in exp2 domain)
    const float sc = which == 0 ? 0.125f * 1.44269504089f : 1.0f;
#pragma unroll
    for (int mt = 0; mt < 4; ++mt) {
#pragma unroll
      for (int nt = 0; nt < 4; ++nt) {
        const int n = nl0 + wn + nt * 16 + cl;
#pragma unroll
        for (int r = 0; r < 4; ++r) {
          const int m = m0 + wm + mt * 16 + rl + r;
          outp[(size_t)m * EMB + n] = f2bf(acc[mt][nt][r] * sc);
        }
      }
    }
  } else {
    // V: write transposed per head: Vt[(b*16+h)*64 + d][s]
#pragma unroll
    for (int mt = 0; mt < 4; ++mt) {
      const int mbase = m0 + wm + mt * 16 + rl;
      const int b = mbase >> 11, s = mbase & 2047;
#pragma unroll
      for (int nt = 0; nt < 4; ++nt) {
        const int n = nl0 + wn + nt * 16 + cl;
        const int h = n >> 6, d = n & 63;
        uint2 o;
        o.x = pkbf(acc[mt][nt][0], acc[mt][nt][1]);
        o.y = pkbf(acc[mt][nt][2], acc[mt][nt][3]);
        *(uint2*)(Vt + ((size_t)((b * 16 + h) * 64 + d) << 11) + s) = o;
      }
    }
  }
}

// ---------- flash attention (causal), 256 thr / 4 waves, 4 blocks/CU ---------
// q-tile 64 (wave w owns q rows w*16..+15). Single-buffered K/V (TLP hides the
// staging drain: 16 waves/CU sustained). LDS exactly 40960 B -> 4 blocks/CU.
// Pl uses XOR chunk swizzle (no pad) so it fits in 8 KB. Grid 1024 with
// 4-group work-balanced mapping: blocks {i,i+256,i+512,i+768} (same CU under
// round-robin dispatch) get qt {31-b, b, 23-b, b+8} -> 34 key-tiles per CU.
__global__ __launch_bounds__(256, 4) void attn(
    const u16* __restrict__ Qb, const u16* __restrict__ Kb,
    const u16* __restrict__ Vt, u16* __restrict__ Ob) {
  __shared__ u16 Kl[128 * 64];    // [key][64], XOR-8 swizzled      (16 KB)
  __shared__ u16 Vl[64 * 128];    // [d][128], XOR-8 swizzled       (16 KB)
  __shared__ u16 Pl[64 * 64];     // [q][64], XOR-8 chunk swizzled  (8 KB)

  const int t = threadIdx.x, w = t >> 6, L = t & 63;
  const int g = L >> 4, cl = L & 15;
  const int qrow = w * 16 + cl;
  const int gk = g ^ (cl & 3);          // swizzled low chunk bits for frag reads
  const int khi = (cl >> 2) & 1;        // swizzled high chunk bit

  // 4-group balanced qt mapping
  const int idx = blockIdx.x;
  const int grp = idx >> 8, slot = idx & 255;
  const int bh = slot & 31, base = slot >> 5;    // base in 0..7
  int qt;
  if      (grp == 0) qt = 31 - base;
  else if (grp == 1) qt = base;
  else if (grp == 2) qt = 23 - base;
  else               qt = base + 8;
  const int b = bh >> 4, h = bh & 15;
  const int q0 = qt * 64;
  const int qglob = q0 + qrow;
  const int nkt = (qt >> 1) + 1;        // 128-key tiles needed
  const bool evenq = (qt & 1) == 0;

  const u16* Qg = Qb + ((size_t)(b * SEQ) << 10) + h * 64;
  const u16* Kg = Kb + ((size_t)(b * SEQ) << 10) + h * 64;
  const u16* Vg = Vt + ((size_t)(bh * 64) << 11);

  // prologue: stage Q (512 chunks) into Pl + K0 (1024) + V0 (1024)
#pragma unroll
  for (int i = 0; i < 2; ++i) {
    const int c = t + i * 256;
    const int row = c >> 3, col = ((c & 7) ^ (row & 7)) * 8;
    g2l16(Qg + ((size_t)(q0 + row) << 10) + col, Pl + c * 8);
  }
#pragma unroll
  for (int i = 0; i < 4; ++i) {
    const int c = t + i * 256;
    const int row = c >> 3, col = ((c & 7) ^ (row & 7)) * 8;
    g2l16(Kg + ((size_t)row << 10) + col, Kl + c * 8);
  }
#pragma unroll
  for (int i = 0; i < 4; ++i) {
    const int c = t + i * 256;
    const int vrow = c >> 4, vsc = ((c & 15) ^ (vrow & 7)) * 8;
    g2l16(Vg + ((size_t)vrow << 11) + vsc, Vl + c * 8);
  }
  wait_vm0();
  __syncthreads();

  short8 qf[2];
#pragma unroll
  for (int ks = 0; ks < 2; ++ks)
    qf[ks] = *(const short8*)(Pl + qrow * 64 + ((ks ^ khi) * 4 + gk) * 8);

  float lp = 0.f;
  f32x4 oacc[4];
#pragma unroll
  for (int dt = 0; dt < 4; ++dt) oacc[dt] = f32x4{0.f, 0.f, 0.f, 0.f};

  for (int kt = 0; kt < nkt; ++kt) {
    if (kt) {
      __syncthreads();                  // waves done with previous K/V tile
      const int k0n = kt * 128;
#pragma unroll
      for (int i = 0; i < 4; ++i) {
        const int c = t + i * 256;
        const int row = c >> 3, col = ((c & 7) ^ (row & 7)) * 8;
        g2l16(Kg + ((size_t)(k0n + row) << 10) + col, Kl + c * 8);
      }
#pragma unroll
      for (int i = 0; i < 4; ++i) {
        const int c = t + i * 256;
        const int vrow = c >> 4, vsc = ((c & 15) ^ (vrow & 7)) * 8;
        g2l16(Vg + ((size_t)vrow << 11) + k0n + vsc, Vl + c * 8);
      }
      wait_vm0();
      __syncthreads();
    }
    const bool last = (kt == nkt - 1);
    const int k0 = kt * 128;

#pragma unroll
    for (int hh = 0; hh < 2; ++hh) {
      const bool skip = last && evenq && (hh == 1);  // fully-masked half
      if (!skip) {
        const bool maskit = last && (evenq ? (hh == 0) : (hh == 1));
        // S^T half: 64 keys x 16 q
        f32x4 sacc[4];
#pragma unroll
        for (int mt = 0; mt < 4; ++mt) sacc[mt] = f32x4{0.f, 0.f, 0.f, 0.f};
#pragma unroll
        for (int ks = 0; ks < 2; ++ks)
#pragma unroll
          for (int mt = 0; mt < 4; ++mt) {
            short8 kf = *(const short8*)(
                Kl + ((hh * 4 + mt) * 16 + cl) * 64 + ((ks ^ khi) * 4 + gk) * 8);
            sacc[mt] = mfma16(kf, qf[ks], sacc[mt]);
          }
        // softmax (exp2 domain, no running max), P into swizzled private rows
#pragma unroll
        for (int mt = 0; mt < 4; ++mt) {
          const int keyg = k0 + hh * 64 + mt * 16 + g * 4;
          float p0 = fexp2(sacc[mt][0]);
          float p1 = fexp2(sacc[mt][1]);
          float p2 = fexp2(sacc[mt][2]);
          float p3 = fexp2(sacc[mt][3]);
          if (maskit) {
            if (keyg + 0 > qglob) p0 = 0.f;
            if (keyg + 1 > qglob) p1 = 0.f;
            if (keyg + 2 > qglob) p2 = 0.f;
            if (keyg + 3 > qglob) p3 = 0.f;
          }
          lp += (p0 + p1) + (p2 + p3);
          uint2 pk;
          pk.x = pkbf(p0, p1);
          pk.y = pkbf(p2, p3);
          const int pchunk = (mt * 2 + (g >> 1)) ^ (cl & 7);
          *(uint2*)(Pl + qrow * 64 + pchunk * 8 + (g & 1) * 4) = pk;
        }
        // O^T half += V^T * P^T
#pragma unroll
        for (int ks = 0; ks < 2; ++ks) {
          short8 pf = *(const short8*)(Pl + qrow * 64 + ((ks ^ khi) * 4 + gk) * 8);
#pragma unroll
          for (int dt = 0; dt < 4; ++dt) {
            short8 vf = *(const short8*)(
                Vl + (dt * 16 + cl) * 128 + (hh * 8 + (ks ^ khi) * 4 + gk) * 8);
            oacc[dt] = mfma16(vf, pf, oacc[dt]);
          }
        }
      }
    }
  }

  // reduce l over the 4 key-quarter lanes, then write O
  float l = lp;
  l += __shfl_xor(l, 16);
  l += __shfl_xor(l, 32);
  const float inv = 1.f / l;
  const size_t qg = (size_t)(b * SEQ + qglob);
#pragma unroll
  for (int dt = 0; dt < 4; ++dt) {
    uint2 o;
    o.x = pkbf(oacc[dt][0] * inv, oacc[dt][1] * inv);
    o.y = pkbf(oacc[dt][2] * inv, oacc[dt][3] * inv);
    *(uint2*)(Ob + (qg << 10) + h * 64 + dt * 16 + g * 4) = o;
  }
}

// ---------------- output projection: fp32 out = Ob * wo^T, 128x64 tiles ------
__global__ __launch_bounds__(256) void gemm_out(const u16* __restrict__ Ab,
                                                const u16* __restrict__ Wb,
                                                float* __restrict__ out) {
  __shared__ u16 Al[2 * 128 * 32];
  __shared__ u16 Bl[2 * 64 * 32];
  const int t = threadIdx.x, L = t & 63, w = t >> 6;
  const int wm = (w >> 1) * 64, wn = (w & 1) * 32;
  const int bx = blockIdx.x;
  const int m0 = (bx & 31) * 128;
  const int n0 = (bx >> 5) * 64;

  f32x4 acc[4][2];
#pragma unroll
  for (int i = 0; i < 4; ++i)
#pragma unroll
    for (int j = 0; j < 2; ++j) acc[i][j] = f32x4{0.f, 0.f, 0.f, 0.f};

  gemm_core_db<2>(Ab, Wb, m0, n0, Al, Bl, acc, t);

  const int rl = (L >> 4) * 4, cl = L & 15;
#pragma unroll
  for (int mt = 0; mt < 4; ++mt)
#pragma unroll
    for (int nt = 0; nt < 2; ++nt) {
      const int n = n0 + wn + nt * 16 + cl;
#pragma unroll
      for (int r = 0; r < 4; ++r) {
        const int m = m0 + wm + mt * 16 + rl + r;
        out[(size_t)m * EMB + n] = acc[mt][nt][r];
      }
    }
}

// ---------------- launch ----------------
extern "C" void kernel_launch(void* const* d_in, const int* in_sizes, int n_in,
                              void* d_out, int out_size, void* d_ws, size_t ws_size,
                              hipStream_t stream) {
  const float* x  = (const float*)d_in[0];
  const float* wq = (const float*)d_in[1];
  const float* wk = (const float*)d_in[2];
  const float* wv = (const float*)d_in[3];
  const float* wo = (const float*)d_in[4];
  float* out = (float*)d_out;

  char* ws = (char*)d_ws;
  u16* xb  = (u16*)(ws);                          // 8 MB  [4096][1024]
  u16* wqb = (u16*)(ws + ((size_t)8  << 20));     // 2 MB
  u16* wkb = (u16*)(ws + ((size_t)10 << 20));     // 2 MB
  u16* wvb = (u16*)(ws + ((size_t)12 << 20));     // 2 MB
  u16* wob = (u16*)(ws + ((size_t)14 << 20));     // 2 MB
  u16* Qb  = (u16*)(ws + ((size_t)16 << 20));     // 8 MB  pre-scaled by 0.125*log2e
  u16* Kb  = (u16*)(ws + ((size_t)24 << 20));     // 8 MB
  u16* Vt  = (u16*)(ws + ((size_t)32 << 20));     // 8 MB  [32*64][2048] transposed
  u16* Ob  = (u16*)(ws + ((size_t)40 << 20));     // 8 MB

  cvt_all<<<8192, 256, 0, stream>>>(x, wq, wk, wv, wo, xb, wqb, wkb, wvb, wob);
  gemm_qkv<<<768, 256, 0, stream>>>(xb, wqb, wkb, wvb, Qb, Kb, Vt);
  attn<<<1024, 256, 0, stream>>>(Qb, Kb, Vt, Ob);
  gemm_out<<<512, 256, 0, stream>>>(Ob, wob, out);
}